// Round 2
// baseline (938.677 us; speedup 1.0000x reference)
//
#include <hip/hip_runtime.h>
#include <hip/hip_bf16.h>

#define NN 131072
#define KK 27
#define CC 32
#define EPSV 1e-5f

// ---- binned-gather configuration ----
#define RB 256                    // output rows per bucket (= per gather block)
#define NB (NN / RB)              // 512 buckets
#define CAPK 384                  // capacity per (bucket, tap) sub-bucket (mean 256, +8 sigma)
#define NSB (NB * KK)             // 13824 sub-buckets

// workspace layout (bytes)
#define WS_STATS   0              // 64 f32
#define WS_WFRAG   256            // 27*1024 bf16 = 55296 B
#define WS_GCOUNT  65536          // 13824 counters, padded to 64 B each = 884736 B
#define WS_BUF     950272         // NSB * CAPK * 4 = 21233664 B
#define WS_NEEDED  (WS_BUF + (size_t)NSB * CAPK * 4)

typedef __bf16 bf16x8 __attribute__((ext_vector_type(8)));
typedef short s16x8 __attribute__((ext_vector_type(8)));
typedef float f32x4 __attribute__((ext_vector_type(4)));

__device__ inline unsigned short f2bf(float f) {
    unsigned int u = __float_as_uint(f);
    u += 0x7FFF + ((u >> 16) & 1);   // round-to-nearest-even
    return (unsigned short)(u >> 16);
}

// ---------------------------------------------------------------------------
// Pass 0: build bf16 MFMA B-fragments for all 27 taps into ws (55 KB).
// B-frag layout for 16x16x32 (verified R1): lane = (n&15)|(quad<<4) holds
// B[quad*8+j][n] at slot j.
__global__ __launch_bounds__(256) void prep_wfrag(
    const float* __restrict__ weight, unsigned short* __restrict__ wf)
{
    for (int p = threadIdx.x; p < KK * 1024; p += 256) {
        const int k  = p >> 10;
        const int ci = (p >> 5) & 31;
        const int c  = p & 31;
        const unsigned short v = f2bf(weight[p]);
        const int chalf = c >> 4;
        const int fl = (c & 15) | ((ci >> 3) << 4);
        const int j = ci & 7;
        wf[((k * 2 + chalf) * 64 + fl) * 8 + j] = v;
    }
}

// ---------------------------------------------------------------------------
// Pass 1: bin every (i,k) contribution by (dest_bucket, k).
// Entry = (i << 8) | (j & 255). 864 blocks * 256 threads * 16 iters = NN*KK.
__global__ __launch_bounds__(256) void bin_kernel(
    const int* __restrict__ neigh, int* __restrict__ gcount, int* __restrict__ buf)
{
    const int tid = blockIdx.x * 256 + threadIdx.x;   // 221184 threads
    #pragma unroll
    for (int it = 0; it < 16; ++it) {
        const int e = tid + it * 221184;
        const int j = neigh[e];
        const unsigned int i = (unsigned int)e / 27u;
        const int k = e - (int)(i * 27u);
        const int kb = (j >> 8) * KK + k;
        const int rank = atomicAdd(&gcount[kb * 16], 1);   // 64B-padded counters
        if (rank < CAPK) buf[kb * CAPK + rank] = ((int)i << 8) | (j & 255);
    }
}

// ---------------------------------------------------------------------------
// Pass 2: per-bucket gather + MFMA + LDS accumulation; fused stats; writeout.
__global__ __launch_bounds__(512) void gather_kernel(
    const float* __restrict__ data, const unsigned short* __restrict__ wf,
    const int* __restrict__ gcount, const int* __restrict__ buf,
    float* __restrict__ out, float* __restrict__ stats)
{
    __shared__ float acc[RB * CC];        // 32 KB f32 accumulator
    __shared__ float red[2][16][32];      // 4 KB stats partials
    __shared__ int cnts[KK];

    const int tid = threadIdx.x;
    const int b = blockIdx.x;

    if (tid < KK) cnts[tid] = min(gcount[(b * KK + tid) * 16], CAPK);
    for (int p = tid; p < RB * CC; p += 512) acc[p] = 0.f;
    __syncthreads();

    const int lane = tid & 63, wv = tid >> 6;
    const int quad = lane >> 4, m = lane & 15, rq = quad << 2;
    const f32x4 zero = {0.f, 0.f, 0.f, 0.f};

    for (int k = 0; k < KK; ++k) {
        const int cnt = cnts[k];
        const int base = (b * KK + k) * CAPK;
        const s16x8* wgk = (const s16x8*)(wf + k * 1024);
        for (int t = wv; t * 16 < cnt; t += 8) {
            const int idx = t * 16 + m;
            const int e = (idx < cnt) ? buf[base + idx] : -1;
            // A-frag: row m of the 16-entry tile, ci slice quad*8..+8
            s16x8 a;
            #pragma unroll
            for (int z = 0; z < 8; ++z) a[z] = 0;
            if (e >= 0) {
                const float* src = data + (size_t)((unsigned)e >> 8) * 32 + quad * 8;
                const float4 v0 = *(const float4*)(src);
                const float4 v1 = *(const float4*)(src + 4);
                a[0] = (short)f2bf(v0.x); a[1] = (short)f2bf(v0.y);
                a[2] = (short)f2bf(v0.z); a[3] = (short)f2bf(v0.w);
                a[4] = (short)f2bf(v1.x); a[5] = (short)f2bf(v1.y);
                a[6] = (short)f2bf(v1.z); a[7] = (short)f2bf(v1.w);
            }
            #pragma unroll
            for (int ch = 0; ch < 2; ++ch) {
                const s16x8 bs = wgk[ch * 64 + lane];   // L1-hot (2 KB/tap)
                f32x4 d = __builtin_amdgcn_mfma_f32_16x16x32_bf16(
                    __builtin_bit_cast(bf16x8, a), __builtin_bit_cast(bf16x8, bs),
                    zero, 0, 0, 0);
                #pragma unroll
                for (int r = 0; r < 4; ++r) {
                    // C/D row rq+r belongs to the entry held by lane rq+r
                    const int er = __shfl(e, rq + r, 64);
                    if (er >= 0)
                        atomicAdd(&acc[(er & 255) * 32 + (ch << 4) + m], d[r]);
                }
            }
        }
    }
    __syncthreads();

    // coalesced writeout of this bucket's 256 rows
    float4* o4 = (float4*)(out + (size_t)b * RB * CC);
    const float4* a4 = (const float4*)acc;
    #pragma unroll
    for (int p = tid; p < RB * CC / 4; p += 512) o4[p] = a4[p];

    // fused per-channel stats
    const int c = tid & 31, rg = tid >> 5;   // rg in [0,16)
    float s = 0.f, s2 = 0.f;
    for (int row = rg; row < RB; row += 16) {
        const float v = acc[row * 32 + c];
        s += v; s2 += v * v;
    }
    red[0][rg][c] = s; red[1][rg][c] = s2;
    __syncthreads();
    if (tid < 32) {
        float S = 0.f, S2 = 0.f;
        #pragma unroll
        for (int g = 0; g < 16; ++g) { S += red[0][g][tid]; S2 += red[1][g][tid]; }
        atomicAdd(&stats[tid], S);
        atomicAdd(&stats[32 + tid], S2);
    }
}

// ---------------------------------------------------------------------------
// Pass 3: y = gamma*(x-mean)*rsqrt(var+eps)+beta, relu — in place.
__global__ __launch_bounds__(256) void bn_relu_kernel(
    float* __restrict__ out, const float* __restrict__ stats,
    const float* __restrict__ gamma, const float* __restrict__ beta)
{
    __shared__ float sc[32], sh[32];
    const int tid = threadIdx.x;
    if (tid < 32) {
        const float mean = stats[tid] * (1.0f / NN);
        const float var  = stats[32 + tid] * (1.0f / NN) - mean * mean;
        const float s = gamma[tid] * rsqrtf(var + EPSV);
        sc[tid] = s;
        sh[tid] = beta[tid] - mean * s;
    }
    __syncthreads();
    const int idx = blockIdx.x * 256 + tid;
    float4 v = ((float4*)out)[idx];
    const int cb = (idx & 7) << 2;
    v.x = fmaxf(v.x * sc[cb]     + sh[cb],     0.f);
    v.y = fmaxf(v.y * sc[cb + 1] + sh[cb + 1], 0.f);
    v.z = fmaxf(v.z * sc[cb + 2] + sh[cb + 2], 0.f);
    v.w = fmaxf(v.w * sc[cb + 3] + sh[cb + 3], 0.f);
    ((float4*)out)[idx] = v;
}

// ===========================================================================
// Fallback path (R1): direct global-atomic scatter — used only if ws is small.
__global__ __launch_bounds__(256) void scatter_kernel(
    const float* __restrict__ data, const float* __restrict__ weight,
    const int* __restrict__ neigh, float* __restrict__ out)
{
    __shared__ unsigned short wfrag[KK * 2 * 64 * 8];
    const int tid = threadIdx.x;
    const int lane = tid & 63;
    const int wv = tid >> 6;
    const int node_base = blockIdx.x * 128;

    for (int p = tid; p < KK * 1024; p += 256) {
        const int k  = p >> 10;
        const int ci = (p >> 5) & 31;
        const int c  = p & 31;
        const unsigned short v = f2bf(weight[p]);
        const int chalf = c >> 4;
        const int fl = (c & 15) | ((ci >> 3) << 4);
        const int j = ci & 7;
        wfrag[(((k << 1) | chalf) * 64 + fl) * 8 + j] = v;
    }
    const int quad = lane >> 4;
    const int m = lane & 15;
    s16x8 afr[2];
    #pragma unroll
    for (int g = 0; g < 2; ++g) {
        const int node = node_base + wv * 32 + g * 16 + m;
        const float* src = data + node * 32 + quad * 8;
        const float4 v0 = *(const float4*)(src);
        const float4 v1 = *(const float4*)(src + 4);
        s16x8 s;
        s[0] = (short)f2bf(v0.x); s[1] = (short)f2bf(v0.y);
        s[2] = (short)f2bf(v0.z); s[3] = (short)f2bf(v0.w);
        s[4] = (short)f2bf(v1.x); s[5] = (short)f2bf(v1.y);
        s[6] = (short)f2bf(v1.z); s[7] = (short)f2bf(v1.w);
        afr[g] = s;
    }
    __syncthreads();
    const int rq = quad << 2;
    const f32x4 zero = {0.f, 0.f, 0.f, 0.f};
    for (int k = 0; k < KK; ++k) {
        int nj[2][4];
        #pragma unroll
        for (int g = 0; g < 2; ++g)
            #pragma unroll
            for (int r = 0; r < 4; ++r) {
                const int node = node_base + wv * 32 + g * 16 + rq + r;
                nj[g][r] = neigh[node * KK + k];
            }
        #pragma unroll
        for (int ch = 0; ch < 2; ++ch) {
            const int t = (k << 1) | ch;
            const s16x8 bs = *(const s16x8*)&wfrag[(t * 64 + lane) * 8];
            const bf16x8 bfr = __builtin_bit_cast(bf16x8, bs);
            const int c = (ch << 4) | m;
            #pragma unroll
            for (int g = 0; g < 2; ++g) {
                f32x4 acc2 = __builtin_amdgcn_mfma_f32_16x16x32_bf16(
                    __builtin_bit_cast(bf16x8, afr[g]), bfr, zero, 0, 0, 0);
                #pragma unroll
                for (int r = 0; r < 4; ++r)
                    __hip_atomic_fetch_add(&out[nj[g][r] * 32 + c], acc2[r],
                                           __ATOMIC_RELAXED, __HIP_MEMORY_SCOPE_AGENT);
            }
        }
    }
}

__global__ __launch_bounds__(256) void stats_kernel(
    const float* __restrict__ out, float* __restrict__ stats)
{
    __shared__ float ls[256], ls2[256];
    const int tid = threadIdx.x;
    const int c = tid & 31, rg = tid >> 5;
    float s = 0.f, s2 = 0.f;
    const int row0 = blockIdx.x * 512;
    #pragma unroll 8
    for (int it = 0; it < 64; ++it) {
        const float v = out[(row0 + it * 8 + rg) * 32 + c];
        s += v; s2 += v * v;
    }
    ls[tid] = s; ls2[tid] = s2;
    __syncthreads();
    if (tid < 32) {
        float S = 0.f, S2 = 0.f;
        #pragma unroll
        for (int r = 0; r < 8; ++r) { S += ls[r * 32 + tid]; S2 += ls2[r * 32 + tid]; }
        atomicAdd(&stats[tid], S);
        atomicAdd(&stats[32 + tid], S2);
    }
}

// ===========================================================================
extern "C" void kernel_launch(void* const* d_in, const int* in_sizes, int n_in,
                              void* d_out, int out_size, void* d_ws, size_t ws_size,
                              hipStream_t stream) {
    const float* data   = (const float*)d_in[0];
    const float* weight = (const float*)d_in[1];
    const float* gamma  = (const float*)d_in[2];
    const float* beta   = (const float*)d_in[3];
    const int*   neigh  = (const int*)d_in[4];
    float* out = (float*)d_out;
    char* ws = (char*)d_ws;
    float* stats = (float*)(ws + WS_STATS);

    if (ws_size >= WS_NEEDED) {
        unsigned short* wf = (unsigned short*)(ws + WS_WFRAG);
        int* gcount = (int*)(ws + WS_GCOUNT);
        int* buf    = (int*)(ws + WS_BUF);
        hipMemsetAsync(ws, 0, WS_BUF, stream);   // stats + gcount (wfrag overwritten)
        prep_wfrag<<<1, 256, 0, stream>>>(weight, wf);
        bin_kernel<<<864, 256, 0, stream>>>(neigh, gcount, buf);
        gather_kernel<<<NB, 512, 0, stream>>>(data, wf, gcount, buf, out, stats);
        bn_relu_kernel<<<(NN * CC / 4) / 256, 256, 0, stream>>>(out, stats, gamma, beta);
    } else {
        hipMemsetAsync(out, 0, (size_t)NN * CC * sizeof(float), stream);
        hipMemsetAsync(stats, 0, 64 * sizeof(float), stream);
        scatter_kernel<<<NN / 128, 256, 0, stream>>>(data, weight, neigh, out);
        stats_kernel<<<NN / 512, 256, 0, stream>>>(out, stats);
        bn_relu_kernel<<<(NN * CC / 4) / 256, 256, 0, stream>>>(out, stats, gamma, beta);
    }
}

// Round 3
// 272.054 us; speedup vs baseline: 3.4503x; 3.4503x over previous
//
#include <hip/hip_runtime.h>
#include <hip/hip_bf16.h>
#include <hip/hip_fp16.h>

#define NN 131072
#define KK 27
#define CC 32
#define EPSV 1e-5f

// workspace layout (bytes): [0,256) f32 stats, [256, 256+8.4MB) f16 accumulator
#define WS_STATS 0
#define WS_ACC   256
#define WS_NEEDED ((size_t)WS_ACC + (size_t)NN * CC * 2)

typedef __bf16 bf16x8 __attribute__((ext_vector_type(8)));
typedef short s16x8 __attribute__((ext_vector_type(8)));
typedef float f32x4 __attribute__((ext_vector_type(4)));

__device__ inline unsigned short f2bf(float f) {
    unsigned int u = __float_as_uint(f);
    u += 0x7FFF + ((u >> 16) & 1);   // round-to-nearest-even
    return (unsigned short)(u >> 16);
}

// ---------------------------------------------------------------------------
// Scatter with packed-f16 atomics. One block = 256 threads = 4 waves; each
// wave owns 32 input nodes (2 MFMA row-groups).
//
// Channel permutation: logical out-channel c is computed by MFMA ch-half
// (c & 1) at physical column (c >> 1). So after the two MFMAs of tap k,
// lane (quad,m) holds logical channels (2m, 2m+1) for rows rq..rq+3 —
// a free __half2 pack, one global_atomic_pk_add_f16 per pair, and the 16
// lanes of a quad cover one contiguous 64 B line of the destination row.
__global__ __launch_bounds__(256) void scatter_kernel(
    const float* __restrict__ data, const float* __restrict__ weight,
    const int* __restrict__ neigh, __half2* __restrict__ acc2)
{
    __shared__ unsigned short wfrag[KK * 2 * 64 * 8];   // 55296 B

    const int tid = threadIdx.x;
    const int lane = tid & 63;
    const int wv = tid >> 6;
    const int node_base = blockIdx.x * 128;

    // ---- Build permuted B-fragments from f32 weight [K][CIN][COUT] ----
    for (int p = tid; p < KK * 1024; p += 256) {
        const int k  = p >> 10;
        const int ci = (p >> 5) & 31;
        const int c  = p & 31;
        const unsigned short v = f2bf(weight[p]);
        const int chalf = c & 1;           // parity -> which MFMA
        const int col   = c >> 1;          // physical column 0..15
        const int fl = col | ((ci >> 3) << 4);
        const int j = ci & 7;
        wfrag[(((k << 1) | chalf) * 64 + fl) * 8 + j] = v;
    }

    // ---- A-fragments: A[m=lane&15][kel=quad*8+j], f32->bf16 inline ----
    const int quad = lane >> 4;
    const int m = lane & 15;
    s16x8 afr[2];
    #pragma unroll
    for (int g = 0; g < 2; ++g) {
        const int node = node_base + wv * 32 + g * 16 + m;
        const float* src = data + node * 32 + quad * 8;
        const float4 v0 = *(const float4*)(src);
        const float4 v1 = *(const float4*)(src + 4);
        s16x8 s;
        s[0] = (short)f2bf(v0.x); s[1] = (short)f2bf(v0.y);
        s[2] = (short)f2bf(v0.z); s[3] = (short)f2bf(v0.w);
        s[4] = (short)f2bf(v1.x); s[5] = (short)f2bf(v1.y);
        s[6] = (short)f2bf(v1.z); s[7] = (short)f2bf(v1.w);
        afr[g] = s;
    }

    __syncthreads();

    const int rq = quad << 2;              // C/D row base: row = rq + reg
    const f32x4 zero = {0.f, 0.f, 0.f, 0.f};

    for (int k = 0; k < KK; ++k) {
        int nj[2][4];
        #pragma unroll
        for (int g = 0; g < 2; ++g)
            #pragma unroll
            for (int r = 0; r < 4; ++r) {
                const int node = node_base + wv * 32 + g * 16 + rq + r;
                nj[g][r] = neigh[node * KK + k];
            }
        const s16x8 bs0 = *(const s16x8*)&wfrag[(((k << 1) | 0) * 64 + lane) * 8];
        const s16x8 bs1 = *(const s16x8*)&wfrag[(((k << 1) | 1) * 64 + lane) * 8];
        #pragma unroll
        for (int g = 0; g < 2; ++g) {
            const f32x4 d0 = __builtin_amdgcn_mfma_f32_16x16x32_bf16(
                __builtin_bit_cast(bf16x8, afr[g]), __builtin_bit_cast(bf16x8, bs0),
                zero, 0, 0, 0);
            const f32x4 d1 = __builtin_amdgcn_mfma_f32_16x16x32_bf16(
                __builtin_bit_cast(bf16x8, afr[g]), __builtin_bit_cast(bf16x8, bs1),
                zero, 0, 0, 0);
            #pragma unroll
            for (int r = 0; r < 4; ++r) {
                __half2 v;
                v.x = __float2half(d0[r]);   // logical channel 2m
                v.y = __float2half(d1[r]);   // logical channel 2m+1
                unsafeAtomicAdd(&acc2[nj[g][r] * 16 + m], v);
            }
        }
    }
}

// ---------------------------------------------------------------------------
// Per-channel sum/sumsq over the f16 accumulator. Block covers 512 rows.
// Thread handles a half2 column (2 channels) across 32 row-iterations.
__global__ __launch_bounds__(256) void stats_kernel(
    const __half2* __restrict__ acc2, float* __restrict__ stats)
{
    __shared__ float ls[16][33], ls2[16][33];   // [rowgroup][channel] (+pad)
    const int tid = threadIdx.x;
    const int c2 = tid & 15, rg = tid >> 4;     // 16 half2-cols x 16 rowgroups
    float sx = 0.f, sy = 0.f, s2x = 0.f, s2y = 0.f;
    const int row0 = blockIdx.x * 512;
    for (int it = 0; it < 32; ++it) {
        const __half2 h = acc2[(row0 + it * 16 + rg) * 16 + c2];
        const float vx = __half2float(h.x), vy = __half2float(h.y);
        sx += vx; sy += vy; s2x += vx * vx; s2y += vy * vy;
    }
    ls[rg][2 * c2] = sx;  ls[rg][2 * c2 + 1] = sy;
    ls2[rg][2 * c2] = s2x; ls2[rg][2 * c2 + 1] = s2y;
    __syncthreads();
    if (tid < 32) {
        float S = 0.f, S2 = 0.f;
        #pragma unroll
        for (int g = 0; g < 16; ++g) { S += ls[g][tid]; S2 += ls2[g][tid]; }
        atomicAdd(&stats[tid], S);
        atomicAdd(&stats[32 + tid], S2);
    }
}

// ---------------------------------------------------------------------------
// y = gamma*(x-mean)*rsqrt(var+eps)+beta, relu. Reads f16 accum, writes f32.
// Each thread: 8 channels (16 B f16 load, 32 B f32 store).
__global__ __launch_bounds__(256) void bn_relu_kernel(
    const __half2* __restrict__ acc2, float* __restrict__ out,
    const float* __restrict__ stats,
    const float* __restrict__ gamma, const float* __restrict__ beta)
{
    __shared__ float sc[32], sh[32];
    const int tid = threadIdx.x;
    if (tid < 32) {
        const float mean = stats[tid] * (1.0f / NN);
        const float var  = stats[32 + tid] * (1.0f / NN) - mean * mean;
        const float s = gamma[tid] * rsqrtf(var + EPSV);
        sc[tid] = s;
        sh[tid] = beta[tid] - mean * s;
    }
    __syncthreads();
    const int idx = blockIdx.x * 256 + tid;      // idx over groups of 4 half2
    const int c0 = (idx & 3) << 3;               // channel base within row
    const __half2 h4[4] = { acc2[idx * 4], acc2[idx * 4 + 1],
                            acc2[idx * 4 + 2], acc2[idx * 4 + 3] };
    float4 o0, o1;
    o0.x = fmaxf(__half2float(h4[0].x) * sc[c0]     + sh[c0],     0.f);
    o0.y = fmaxf(__half2float(h4[0].y) * sc[c0 + 1] + sh[c0 + 1], 0.f);
    o0.z = fmaxf(__half2float(h4[1].x) * sc[c0 + 2] + sh[c0 + 2], 0.f);
    o0.w = fmaxf(__half2float(h4[1].y) * sc[c0 + 3] + sh[c0 + 3], 0.f);
    o1.x = fmaxf(__half2float(h4[2].x) * sc[c0 + 4] + sh[c0 + 4], 0.f);
    o1.y = fmaxf(__half2float(h4[2].y) * sc[c0 + 5] + sh[c0 + 5], 0.f);
    o1.z = fmaxf(__half2float(h4[3].x) * sc[c0 + 6] + sh[c0 + 6], 0.f);
    o1.w = fmaxf(__half2float(h4[3].y) * sc[c0 + 7] + sh[c0 + 7], 0.f);
    ((float4*)out)[idx * 2]     = o0;
    ((float4*)out)[idx * 2 + 1] = o1;
}

// ===========================================================================
// Fallback (R1, f32 atomics into d_out) — only if ws is too small.
__global__ __launch_bounds__(256) void scatter_f32_kernel(
    const float* __restrict__ data, const float* __restrict__ weight,
    const int* __restrict__ neigh, float* __restrict__ out)
{
    __shared__ unsigned short wfrag[KK * 2 * 64 * 8];
    const int tid = threadIdx.x;
    const int lane = tid & 63;
    const int wv = tid >> 6;
    const int node_base = blockIdx.x * 128;
    for (int p = tid; p < KK * 1024; p += 256) {
        const int k  = p >> 10;
        const int ci = (p >> 5) & 31;
        const int c  = p & 31;
        const unsigned short v = f2bf(weight[p]);
        const int chalf = c >> 4;
        const int fl = (c & 15) | ((ci >> 3) << 4);
        const int j = ci & 7;
        wfrag[(((k << 1) | chalf) * 64 + fl) * 8 + j] = v;
    }
    const int quad = lane >> 4;
    const int m = lane & 15;
    s16x8 afr[2];
    #pragma unroll
    for (int g = 0; g < 2; ++g) {
        const int node = node_base + wv * 32 + g * 16 + m;
        const float* src = data + node * 32 + quad * 8;
        const float4 v0 = *(const float4*)(src);
        const float4 v1 = *(const float4*)(src + 4);
        s16x8 s;
        s[0] = (short)f2bf(v0.x); s[1] = (short)f2bf(v0.y);
        s[2] = (short)f2bf(v0.z); s[3] = (short)f2bf(v0.w);
        s[4] = (short)f2bf(v1.x); s[5] = (short)f2bf(v1.y);
        s[6] = (short)f2bf(v1.z); s[7] = (short)f2bf(v1.w);
        afr[g] = s;
    }
    __syncthreads();
    const int rq = quad << 2;
    const f32x4 zero = {0.f, 0.f, 0.f, 0.f};
    for (int k = 0; k < KK; ++k) {
        int nj[2][4];
        #pragma unroll
        for (int g = 0; g < 2; ++g)
            #pragma unroll
            for (int r = 0; r < 4; ++r) {
                const int node = node_base + wv * 32 + g * 16 + rq + r;
                nj[g][r] = neigh[node * KK + k];
            }
        #pragma unroll
        for (int ch = 0; ch < 2; ++ch) {
            const s16x8 bs = *(const s16x8*)&wfrag[((((k << 1) | ch)) * 64 + lane) * 8];
            const bf16x8 bfr = __builtin_bit_cast(bf16x8, bs);
            const int c = (ch << 4) | m;
            #pragma unroll
            for (int g = 0; g < 2; ++g) {
                f32x4 a2 = __builtin_amdgcn_mfma_f32_16x16x32_bf16(
                    __builtin_bit_cast(bf16x8, afr[g]), bfr, zero, 0, 0, 0);
                #pragma unroll
                for (int r = 0; r < 4; ++r)
                    __hip_atomic_fetch_add(&out[nj[g][r] * 32 + c], a2[r],
                                           __ATOMIC_RELAXED, __HIP_MEMORY_SCOPE_AGENT);
            }
        }
    }
}

__global__ __launch_bounds__(256) void stats_f32_kernel(
    const float* __restrict__ out, float* __restrict__ stats)
{
    __shared__ float ls[256], ls2[256];
    const int tid = threadIdx.x;
    const int c = tid & 31, rg = tid >> 5;
    float s = 0.f, s2 = 0.f;
    const int row0 = blockIdx.x * 512;
    for (int it = 0; it < 64; ++it) {
        const float v = out[(row0 + it * 8 + rg) * 32 + c];
        s += v; s2 += v * v;
    }
    ls[tid] = s; ls2[tid] = s2;
    __syncthreads();
    if (tid < 32) {
        float S = 0.f, S2 = 0.f;
        #pragma unroll
        for (int r = 0; r < 8; ++r) { S += ls[r * 32 + tid]; S2 += ls2[r * 32 + tid]; }
        atomicAdd(&stats[tid], S);
        atomicAdd(&stats[32 + tid], S2);
    }
}

__global__ __launch_bounds__(256) void bn_relu_f32_kernel(
    float* __restrict__ out, const float* __restrict__ stats,
    const float* __restrict__ gamma, const float* __restrict__ beta)
{
    __shared__ float sc[32], sh[32];
    const int tid = threadIdx.x;
    if (tid < 32) {
        const float mean = stats[tid] * (1.0f / NN);
        const float var  = stats[32 + tid] * (1.0f / NN) - mean * mean;
        const float s = gamma[tid] * rsqrtf(var + EPSV);
        sc[tid] = s;
        sh[tid] = beta[tid] - mean * s;
    }
    __syncthreads();
    const int idx = blockIdx.x * 256 + tid;
    float4 v = ((float4*)out)[idx];
    const int cb = (idx & 7) << 2;
    v.x = fmaxf(v.x * sc[cb]     + sh[cb],     0.f);
    v.y = fmaxf(v.y * sc[cb + 1] + sh[cb + 1], 0.f);
    v.z = fmaxf(v.z * sc[cb + 2] + sh[cb + 2], 0.f);
    v.w = fmaxf(v.w * sc[cb + 3] + sh[cb + 3], 0.f);
    ((float4*)out)[idx] = v;
}

// ===========================================================================
extern "C" void kernel_launch(void* const* d_in, const int* in_sizes, int n_in,
                              void* d_out, int out_size, void* d_ws, size_t ws_size,
                              hipStream_t stream) {
    const float* data   = (const float*)d_in[0];
    const float* weight = (const float*)d_in[1];
    const float* gamma  = (const float*)d_in[2];
    const float* beta   = (const float*)d_in[3];
    const int*   neigh  = (const int*)d_in[4];
    float* out = (float*)d_out;
    char* ws = (char*)d_ws;
    float* stats = (float*)(ws + WS_STATS);

    if (ws_size >= WS_NEEDED) {
        __half2* acc2 = (__half2*)(ws + WS_ACC);
        hipMemsetAsync(ws, 0, WS_NEEDED, stream);   // stats + f16 accumulator
        scatter_kernel<<<NN / 128, 256, 0, stream>>>(data, weight, neigh, acc2);
        stats_kernel<<<NN / 512, 256, 0, stream>>>(acc2, stats);
        bn_relu_kernel<<<(NN * CC / 8) / 256, 256, 0, stream>>>(acc2, out, stats, gamma, beta);
    } else {
        hipMemsetAsync(out, 0, (size_t)NN * CC * sizeof(float), stream);
        hipMemsetAsync(stats, 0, 64 * sizeof(float), stream);
        scatter_f32_kernel<<<NN / 128, 256, 0, stream>>>(data, weight, neigh, out);
        stats_f32_kernel<<<NN / 512, 256, 0, stream>>>(out, stats);
        bn_relu_f32_kernel<<<(NN * CC / 4) / 256, 256, 0, stream>>>(out, stats, gamma, beta);
    }
}